// Round 11
// baseline (206.268 us; speedup 1.0000x reference)
//
#include <hip/hip_runtime.h>
#include <hip/hip_bf16.h>
#include <math.h>

// MultiWindowAttention B=4,L=2048,H=8,E=D=64 fp32; w = 32<<(h&3).
// Round 11: barrier-free persistent-wave kernel with per-wave LPT queue.
//   Each wave = 16 queries of one (b,h), iterates its band in 16-key steps:
//     S^T = K.Q^T  (mfma_f32_16x16x32_bf16; A=K rows, B=Q^T — direct global)
//     O^T = V^T.P^T (mfma_f32_16x16x16f16; A=V^T coalesced direct global,
//                    B=P^T = S^T's C-layout, stays in registers)
//   No LDS, no __syncthreads; 4096 items pulled biggest-window-first from
//   an atomic queue by each wave independently (dispatch-mapping immune).

#define LL 2048
#define HH 8
#define EE 64
#define DD 64
#define RS (HH * EE)    // 512 floats between consecutive seq positions
#define NIT 4096        // 16-query items: 4 b x 8 h x 128

typedef __attribute__((ext_vector_type(8))) short short8;
typedef __attribute__((ext_vector_type(4))) float floatx4;
typedef __attribute__((ext_vector_type(4))) _Float16 half4;
typedef __attribute__((ext_vector_type(2))) __fp16 fp16x2;

static __device__ __forceinline__ unsigned packh2(float a, float b) {
    union { fp16x2 h; unsigned u; } v;
    v.h = __builtin_amdgcn_cvt_pkrtz(a, b);
    return v.u;
}
static __device__ __forceinline__ unsigned packbf2(float a, float b) {
    union { __hip_bfloat162 h; unsigned u; } v;
    v.h = __float22bfloat162_rn(make_float2(a, b));
    return v.u;
}
// 8 consecutive fp32 -> bf16 short8 (half of a 16x16x32 A/B fragment).
static __device__ __forceinline__ short8 ldbf8(const float* p) {
    float4 a = *(const float4*)p;
    float4 b = *(const float4*)(p + 4);
    union { short8 s; unsigned u[4]; } f;
    f.u[0] = packbf2(a.x, a.y); f.u[1] = packbf2(a.z, a.w);
    f.u[2] = packbf2(b.x, b.y); f.u[3] = packbf2(b.z, b.w);
    return f.s;
}

__global__ __launch_bounds__(256, 4) void mwa_r11(
    const float* __restrict__ Q,
    const float* __restrict__ K,
    const float* __restrict__ V,
    float* __restrict__ O,
    int* __restrict__ cnt)
{
    const int lane = threadIdx.x & 63;
    const int quad = lane >> 4;
    const int l15  = lane & 15;
    const float scale = 0.125f;

    for (;;) {
        int idx = 0;
        if (lane == 0) idx = atomicAdd(cnt, 1);
        idx = __shfl(idx, 0, 64);
        if (idx >= NIT) return;

        // ---- LPT decode: idx 0..1023 -> w=256, then 128, 64, 32 ----
        const int pr  = 3 - (idx >> 10);
        const int sub = idx & 1023;
        const int b   = sub >> 8;
        const int hh  = (sub >> 7) & 1;
        const int it  = sub & 127;
        const int h   = pr + (hh << 2);
        const int w   = 32 << pr;
        const int qi0 = it << 4;

        const float* Qb = Q + ((size_t)b * LL * HH + h) * EE;
        const float* Kb = K + ((size_t)b * LL * HH + h) * EE;
        const float* Vb = V + ((size_t)b * LL * HH + h) * DD;
        float*       Ob = O + ((size_t)b * LL * HH + h) * DD;

        // ---- Q^T B-frag (B[k=e][n=q]): lane q=l15, e=quad*8+t ----
        const float* qrow = Qb + (size_t)(qi0 + l15) * RS + quad * 8;
        const short8 qf0 = ldbf8(qrow);
        const short8 qf1 = ldbf8(qrow + 32);

        const int jlo = max(0, qi0 - w);
        const int jhi = min(LL - 16, qi0 + w);   // last 16-aligned step start
        const int iq  = qi0 + l15;

        floatx4 acc[4] = {};    // O^T accumulator: [d-tile][reg], C layout
        float lsum = 0.f;

        for (int j0 = jlo; j0 <= jhi; j0 += 16) {
            // ---- S^T = K.Q^T (A = K rows: lane j=l15, e=quad*8+t) ----
            const float* krow = Kb + (size_t)(j0 + l15) * RS + quad * 8;
            short8 k0 = ldbf8(krow);
            short8 k1 = ldbf8(krow + 32);
            floatx4 st = {};
            st = __builtin_amdgcn_mfma_f32_16x16x32_bf16(k0, qf0, st, 0, 0, 0);
            st = __builtin_amdgcn_mfma_f32_16x16x32_bf16(k1, qf1, st, 0, 0, 0);

            // ---- mask (edge steps only) + exp -> P^T (B-frag, in regs) ----
            const bool full = (j0 >= qi0 + 15 - w) && (j0 <= qi0 + w - 15);
            float p[4];
#pragma unroll
            for (int r = 0; r < 4; ++r) {
                float x = st[r] * scale;
                if (!full) {
                    const int di = iq - (j0 + quad * 4 + r);
                    x = (di <= w && di >= -w) ? x : -INFINITY;
                }
                p[r] = __expf(x);
                lsum += p[r];
            }
            union { half4 v; unsigned u[2]; } pu;
            pu.u[0] = packh2(p[0], p[1]);
            pu.u[1] = packh2(p[2], p[3]);

            // ---- O^T += V^T.P^T (A = V^T, coalesced: lane d=l15, j=quad*4+i) ----
            const float* vrow = Vb + (size_t)(j0 + quad * 4) * RS + l15;
#pragma unroll
            for (int nt = 0; nt < 4; ++nt) {
                const float v0 = vrow[nt * 16];
                const float v1 = vrow[RS + nt * 16];
                const float v2 = vrow[2 * RS + nt * 16];
                const float v3 = vrow[3 * RS + nt * 16];
                union { half4 v; unsigned u[2]; } vu;
                vu.u[0] = packh2(v0, v1);
                vu.u[1] = packh2(v2, v3);
                acc[nt] = __builtin_amdgcn_mfma_f32_16x16x16f16(vu.v, pu.v, acc[nt], 0, 0, 0);
            }
        }

        // ---- epilogue: lsum over quads; rinv is lane-local (q = l15) ----
        lsum += __shfl_xor(lsum, 16, 64);
        lsum += __shfl_xor(lsum, 32, 64);
        const float rinv = 1.0f / lsum;

        float* orow = Ob + (size_t)(qi0 + l15) * RS + quad * 4;
#pragma unroll
        for (int nt = 0; nt < 4; ++nt) {
            float4 o;
            o.x = acc[nt][0] * rinv;
            o.y = acc[nt][1] * rinv;
            o.z = acc[nt][2] * rinv;
            o.w = acc[nt][3] * rinv;
            *(float4*)(orow + nt * 16) = o;
        }
    }
}

extern "C" void kernel_launch(void* const* d_in, const int* in_sizes, int n_in,
                              void* d_out, int out_size, void* d_ws, size_t ws_size,
                              hipStream_t stream)
{
    const float* Q = (const float*)d_in[0];
    const float* K = (const float*)d_in[1];
    const float* V = (const float*)d_in[2];
    float* O = (float*)d_out;
    int* cnt = (int*)d_ws;

    hipMemsetAsync(cnt, 0, sizeof(int), stream);   // queue head

    dim3 grid(1024), block(256);   // 4096 waves; per-wave LPT queue
    hipLaunchKernelGGL(mwa_r11, grid, block, 0, stream, Q, K, V, O, cnt);
}